// Round 18
// baseline (164.745 us; speedup 1.0000x reference)
//
#include <hip/hip_runtime.h>
#include <hip/hip_bf16.h>
#include <math.h>

#define NB 16
#define C_IN 64
#define C_OUT 64
#define HH 128
#define WW 128
#define MAX_SHIFT 4.0f

typedef __attribute__((ext_vector_type(8))) short bf16x8;
typedef __attribute__((ext_vector_type(4))) float f32x4;
typedef __attribute__((ext_vector_type(4))) unsigned int u32x4;

__device__ inline unsigned short bf16_rne(float f) {
    unsigned u = __builtin_bit_cast(unsigned, f);
    u += 0x7fffu + ((u >> 16) & 1u);
    return (unsigned short)(u >> 16);
}
__device__ inline unsigned pack_bf16x2(float lo, float hi) {
    unsigned ul = __builtin_bit_cast(unsigned, lo);
    unsigned uh = __builtin_bit_cast(unsigned, hi);
    ul += 0x7fffu + ((ul >> 16) & 1u);
    uh += 0x7fffu + ((uh >> 16) & 1u);
    return (ul >> 16) | (uh & 0xffff0000u);
}

// =====================================================================
// PASS 1: bilinear + powers -> xsp[kb6][n][h][w][32] bf16 (kb-major, 100.7MB)
//   k = p*64 + c  =>  kb = 2p + cg,  slot = c%32
//   block = (cg, n, h); XCD-chunk-swizzled so neighbor-h share an L2
// =====================================================================
#define VSTR 34   // u16 stride per w (17 u32, odd -> conflict-free)

__global__ __launch_bounds__(256)
void shift_pow3(const float* __restrict__ x, const float* __restrict__ shifts,
                unsigned short* __restrict__ xsp) {
    __shared__ unsigned short row[128 * VSTR];   // 8,704 B
    __shared__ float s_fx[C_IN], s_fy[C_IN];
    __shared__ int s_dx[C_IN], s_dy[C_IN];

    // chunked bijective XCD swizzle: 4096 = 8 * 512
    int bid0 = blockIdx.x;
    int bid = (bid0 & 7) * 512 + (bid0 >> 3);
    int h  = bid & 127;
    int n  = (bid >> 7) & 15;
    int cg = bid >> 11;
    int tid = threadIdx.x;
    int wv = tid >> 6;
    int l  = tid & 63;

    if (tid < C_IN) {
        float sx = shifts[2 * tid] * MAX_SHIFT;
        float sy = shifts[2 * tid + 1] * MAX_SHIFT;
        float fx0 = floorf(sx), fy0 = floorf(sy);
        s_dx[tid] = (int)fx0; s_dy[tid] = (int)fy0;
        s_fx[tid] = sx - fx0;  s_fy[tid] = sy - fy0;
    }
    __syncthreads();

    const float* xn = x + (size_t)n * (C_IN * HH * WW);

    #pragma unroll 4
    for (int it = 0; it < 8; ++it) {
        int c32 = it * 4 + wv;                 // 0..31, wave-uniform
        int c   = cg * 32 + c32;
        int dx = s_dx[c], dy = s_dy[c];
        float fx = s_fx[c], fy = s_fy[c];
        const float* xp = xn + (size_t)c * (HH * WW);
        int y0 = h + dy, y1 = y0 + 1;
        bool vy0 = ((unsigned)y0 < (unsigned)HH);
        bool vy1 = ((unsigned)y1 < (unsigned)HH);
        const float* r0 = xp + y0 * WW;
        const float* r1 = xp + y1 * WW;

        #pragma unroll
        for (int hf = 0; hf < 2; ++hf) {
            int w = hf * 64 + l;
            int x0 = w + dx, x1 = x0 + 1;
            bool vx0 = ((unsigned)x0 < (unsigned)WW);
            bool vx1 = ((unsigned)x1 < (unsigned)WW);
            float v00 = (vy0 && vx0) ? r0[x0] : 0.f;
            float v01 = (vy0 && vx1) ? r0[x1] : 0.f;
            float v10 = (vy1 && vx0) ? r1[x0] : 0.f;
            float v11 = (vy1 && vx1) ? r1[x1] : 0.f;
            float v = (1.f - fy) * ((1.f - fx) * v00 + fx * v01)
                    + fy * ((1.f - fx) * v10 + fx * v11);
            row[w * VSTR + c32] = bf16_rne(v);
        }
    }
    __syncthreads();

    // writeout: 3 kb-slabs; each 2048 u32 = 8KB contiguous; powers on the fly
    const unsigned* rp = (const unsigned*)row;     // stride 17 u32 per w
    unsigned* xsp32 = (unsigned*)xsp;
    #pragma unroll 1
    for (int p = 0; p < 3; ++p) {
        int kb = p * 2 + cg;
        unsigned* dst = xsp32 + (size_t)(kb * (NB * HH) + n * HH + h) * 2048;
        #pragma unroll
        for (int itw = 0; itw < 8; ++itw) {
            int o32 = itw * 256 + tid;        // 0..2047
            int wl = o32 >> 4;
            int c4 = o32 & 15;
            unsigned u = rp[wl * 17 + c4];
            if (p != 0) {
                float f0 = __builtin_bit_cast(float, u << 16);
                float f1 = __builtin_bit_cast(float, u & 0xffff0000u);
                float r0 = f0 * f0, r1 = f1 * f1;
                if (p == 2) { r0 *= f0; r1 *= f1; }
                u = pack_bf16x2(r0, r1);
            }
            dst[o32] = u;
        }
    }
}

// =====================================================================
// weight prep: [t9][kb6][mf4][lane64][e8] bf16 ; k = kb*32 + slot
// =====================================================================
__global__ void prep_w2(const float* __restrict__ w, unsigned short* __restrict__ wbuf) {
    int id = blockIdx.x * 256 + threadIdx.x;   // < 110592
    int e = id & 7;
    int l = (id >> 3) & 63;
    int f = id >> 9;          // 0..215
    int mf = f & 3;
    int f2 = f >> 2;          // 0..53
    int kb = f2 % 6;
    int t  = f2 / 6;
    int k  = kb * 32 + (l >> 4) * 8 + e;   // 0..191
    int p  = k >> 6;
    int c  = k & 63;
    int co = mf * 16 + (l & 15);
    wbuf[id] = bf16_rne(w[(co * 192 + p * 64 + c) * 9 + t]);
}

// =====================================================================
// PASS 2: conv2h — BARRIER-FREE, wave-private LDS regions.
//   Each wave stages + reads its OWN 7x18-px region (halo rows duplicated).
//   DS ops in-order per wave => no __syncthreads anywhere.
//   16x16 tile, grid 1024, kb-major xsp. LDS 4 x 11088 B = 44,352 B.
// =====================================================================
#define WREG 11088   // 7*18*88 bytes per wave region

__global__ __launch_bounds__(256, 2)
void conv2h(const unsigned short* __restrict__ xsp,
            const unsigned short* __restrict__ wbuf,
            const float* __restrict__ bias,
            float* __restrict__ out) {
    __shared__ unsigned short tile[4 * WREG / 2];   // 44,352 B

    int bid = blockIdx.x;
    int wg = (bid & 7) * 128 + (bid >> 3);   // bijective XCD swizzle (1024 = 8*128)
    int n  = wg >> 6;
    int t6 = wg & 63;
    int i0 = (t6 >> 3) * 16;
    int j0 = (t6 & 7) * 16;

    int tid = threadIdx.x;
    int l  = tid & 63;
    int wv = tid >> 6;
    int lm = l & 15;
    int lg = l >> 4;

    f32x4 acc[4][4];      // [mf][nf=row]
    #pragma unroll
    for (int mf = 0; mf < 4; ++mf) {
        #pragma unroll
        for (int r = 0; r < 4; ++r) {
            float bv = bias[mf * 16 + lg * 4 + r];
            #pragma unroll
            for (int nf = 0; nf < 4; ++nf) acc[mf][nf][r] = bv;
        }
    }

    char* wbase = (char*)tile + wv * WREG;
    int lds_rd = lm * 88 + lg * 16;   // + ((nf+ky)*18 + kx)*88

    // precompute per-item staging geometry (8 items of 16B per lane)
    int soff[8];   // element offset into slab; -1 = skip, -2 = zero-fill
    int loff[8];   // byte offset within wave region
    #pragma unroll
    for (int it = 0; it < 8; ++it) {
        int item = it * 64 + l;          // < 504 = 126 px * 4 subs
        soff[it] = -1;
        loff[it] = 0;
        if (item < 504) {
            int px = item >> 2, sub = item & 3;
            int q = px / 18, c = px - q * 18;
            int gi = i0 - 1 + wv * 4 + q;
            int gj = j0 - 1 + c;
            loff[it] = px * 88 + sub * 16;
            if ((unsigned)gi < (unsigned)HH && (unsigned)gj < (unsigned)WW)
                soff[it] = (gi * WW + gj) * 32 + sub * 8;
            else
                soff[it] = -2;
        }
    }

    #pragma unroll 1
    for (int kb = 0; kb < 6; ++kb) {
        const unsigned short* xr = xsp + (size_t)(kb * NB + n) * (HH * WW * 32);

        // ---- stage this wave's private region (no barrier!) ----
        #pragma unroll
        for (int it = 0; it < 8; ++it) {
            if (soff[it] != -1) {
                u32x4 d = {0, 0, 0, 0};
                if (soff[it] >= 0) d = *(const u32x4*)(xr + soff[it]);
                *(u32x4*)(wbase + loff[it]) = d;
            }
        }

        // ---- compute: 9 taps x 4 nf x 4 mf MFMAs ----
        bf16x8 Af[4];
        #pragma unroll
        for (int mf = 0; mf < 4; ++mf)
            Af[mf] = *(const bf16x8*)(wbuf + (size_t)((0 * 6 + kb) * 4 + mf) * 512 + l * 8);

        #pragma unroll 1
        for (int t = 0; t < 9; ++t) {
            bf16x8 Afn[4];
            int tn = (t < 8) ? t + 1 : t;
            #pragma unroll
            for (int mf = 0; mf < 4; ++mf)
                Afn[mf] = *(const bf16x8*)(wbuf + (size_t)((tn * 6 + kb) * 4 + mf) * 512 + l * 8);

            int ky = t / 3, kx = t - ky * 3;
            #pragma unroll
            for (int nf = 0; nf < 4; ++nf) {
                int off = lds_rd + ((nf + ky) * 18 + kx) * 88;
                bf16x8 bfrag = *(const bf16x8*)(wbase + off);
                #pragma unroll
                for (int mf = 0; mf < 4; ++mf)
                    acc[mf][nf] = __builtin_amdgcn_mfma_f32_16x16x32_bf16(Af[mf], bfrag, acc[mf][nf], 0, 0, 0);
            }
            #pragma unroll
            for (int mf = 0; mf < 4; ++mf) Af[mf] = Afn[mf];
        }
    }

    // ---- epilogue ----
    #pragma unroll
    for (int mf = 0; mf < 4; ++mf) {
        #pragma unroll
        for (int nf = 0; nf < 4; ++nf) {
            int rowi = i0 + wv * 4 + nf;
            int col = j0 + lm;
            #pragma unroll
            for (int r = 0; r < 4; ++r) {
                int co = mf * 16 + lg * 4 + r;
                out[(((size_t)n * C_OUT + co) * HH + rowi) * WW + col] = acc[mf][nf][r];
            }
        }
    }
}

// =====================================================================
// Fallback: fused kernel (needs only 216 KB ws)
// =====================================================================
#define S_PX 100

__global__ void prep_w3(const float* __restrict__ w, unsigned short* __restrict__ wbuf) {
    int id = blockIdx.x * 256 + threadIdx.x;
    int e = id & 7;
    int l = (id >> 3) & 63;
    int f = id >> 9;
    int mf = f & 3;
    int f2 = f >> 2;
    int kb = f2 % 6;
    int t  = f2 / 6;
    int cg = kb / 3;
    int p  = kb - cg * 3;
    int cl = (l >> 4) * 8 + e;
    int co = mf * 16 + (l & 15);
    wbuf[id] = bf16_rne(w[(co * 192 + p * 64 + cg * 32 + cl) * 9 + t]);
}

__global__ __launch_bounds__(256, 2)
void conv_f(const float* __restrict__ x,
            const float* __restrict__ shifts,
            const unsigned short* __restrict__ wbuf,
            const float* __restrict__ bias,
            float* __restrict__ out) {
    __shared__ unsigned short tile[324 * S_PX];
    __shared__ float s_fx[C_IN], s_fy[C_IN];
    __shared__ int s_dx[C_IN], s_dy[C_IN];

    int bid = blockIdx.x;
    int wg = (bid & 7) * 128 + (bid >> 3);
    int n  = wg >> 6;
    int t6 = wg & 63;
    int i0 = (t6 >> 3) * 16;
    int j0 = (t6 & 7) * 16;

    int tid = threadIdx.x;
    int l  = tid & 63;
    int wv = tid >> 6;
    int lm = l & 15;
    int lg = l >> 4;

    if (tid < C_IN) {
        float sx = shifts[2 * tid] * MAX_SHIFT;
        float sy = shifts[2 * tid + 1] * MAX_SHIFT;
        float fx0 = floorf(sx), fy0 = floorf(sy);
        s_dx[tid] = (int)fx0; s_dy[tid] = (int)fy0;
        s_fx[tid] = sx - fx0;  s_fy[tid] = sy - fy0;
    }

    f32x4 acc[4][4];
    #pragma unroll
    for (int mf = 0; mf < 4; ++mf) {
        #pragma unroll
        for (int r = 0; r < 4; ++r) {
            float bv = bias[mf * 16 + lg * 4 + r];
            #pragma unroll
            for (int nf = 0; nf < 4; ++nf) acc[mf][nf][r] = bv;
        }
    }

    const float* xn = x + (size_t)n * (C_IN * HH * WW);

    #pragma unroll 1
    for (int cg = 0; cg < 2; ++cg) {
        __syncthreads();
        #pragma unroll 2
        for (int it = 0; it < 21; ++it) {
            int item = it * 256 + tid;
            if (item < 5184) {
                int cl  = item / 162;
                int rem = item - cl * 162;
                int rp  = rem / 18;
                int cc  = rem - rp * 18;
                int c   = cg * 32 + cl;
                int dx = s_dx[c], dy = s_dy[c];
                float fx = s_fx[c], fy = s_fy[c];
                const float* xp = xn + (size_t)c * (HH * WW);

                int gj  = j0 - 1 + cc;
                int xx0 = gj + dx, xx1 = xx0 + 1;
                bool vx0 = ((unsigned)xx0 < (unsigned)WW);
                bool vx1 = ((unsigned)xx1 < (unsigned)WW);
                int gi0 = i0 - 1 + rp * 2;
                int y0  = gi0 + dy;
                bool vyA = ((unsigned)y0 < (unsigned)HH);
                bool vyB = ((unsigned)(y0 + 1) < (unsigned)HH);
                bool vyC = ((unsigned)(y0 + 2) < (unsigned)HH);
                const float* rA = xp + y0 * WW;
                const float* rB = rA + WW;
                const float* rC = rB + WW;
                float m0 = (vyA && vx0) ? rA[xx0] : 0.f;
                float m1 = (vyA && vx1) ? rA[xx1] : 0.f;
                float m2 = (vyB && vx0) ? rB[xx0] : 0.f;
                float m3 = (vyB && vx1) ? rB[xx1] : 0.f;
                float m4 = (vyC && vx0) ? rC[xx0] : 0.f;
                float m5 = (vyC && vx1) ? rC[xx1] : 0.f;
                float hA = (1.f - fx) * m0 + fx * m1;
                float hB = (1.f - fx) * m2 + fx * m3;
                float hC = (1.f - fx) * m4 + fx * m5;
                float vT = (1.f - fy) * hA + fy * hB;
                float vU = (1.f - fy) * hB + fy * hC;
                if (!((unsigned)gj < (unsigned)WW))        { vT = 0.f; vU = 0.f; }
                if (!((unsigned)gi0 < (unsigned)HH))       vT = 0.f;
                if (!((unsigned)(gi0 + 1) < (unsigned)HH)) vU = 0.f;

                float t2 = vT * vT, t3 = t2 * vT;
                float u2 = vU * vU, u3 = u2 * vU;
                unsigned short* recT = tile + (rp * 2 * 18 + cc) * S_PX;
                unsigned short* recU = recT + 18 * S_PX;
                recT[cl]      = bf16_rne(vT);
                recT[32 + cl] = bf16_rne(t2);
                recT[64 + cl] = bf16_rne(t3);
                recU[cl]      = bf16_rne(vU);
                recU[32 + cl] = bf16_rne(u2);
                recU[64 + cl] = bf16_rne(u3);
            }
        }
        __syncthreads();

        #pragma unroll 1
        for (int p = 0; p < 3; ++p) {
            int kb = cg * 3 + p;
            #pragma unroll 1
            for (int t = 0; t < 9; ++t) {
                bf16x8 Af[4];
                #pragma unroll
                for (int mf = 0; mf < 4; ++mf)
                    Af[mf] = *(const bf16x8*)(wbuf + (size_t)((t * 6 + kb) * 4 + mf) * 512 + l * 8);

                int ky = t / 3, kx = t - ky * 3;
                #pragma unroll
                for (int nf = 0; nf < 4; ++nf) {
                    int off = ((wv * 4 + nf + ky) * 18 + (lm + kx)) * 200 + p * 64 + lg * 16;
                    bf16x8 bfrag = *(const bf16x8*)((const char*)tile + off);
                    #pragma unroll
                    for (int mf = 0; mf < 4; ++mf)
                        acc[mf][nf] = __builtin_amdgcn_mfma_f32_16x16x32_bf16(Af[mf], bfrag, acc[mf][nf], 0, 0, 0);
                }
            }
        }
    }

    #pragma unroll
    for (int mf = 0; mf < 4; ++mf) {
        #pragma unroll
        for (int nf = 0; nf < 4; ++nf) {
            int rowi = i0 + wv * 4 + nf;
            int col = j0 + lm;
            #pragma unroll
            for (int r = 0; r < 4; ++r) {
                int co = mf * 16 + lg * 4 + r;
                out[(((size_t)n * C_OUT + co) * HH + rowi) * WW + col] = acc[mf][nf][r];
            }
        }
    }
}

extern "C" void kernel_launch(void* const* d_in, const int* in_sizes, int n_in,
                              void* d_out, int out_size, void* d_ws, size_t ws_size,
                              hipStream_t stream) {
    (void)in_sizes; (void)n_in; (void)out_size;
    const float* x      = (const float*)d_in[0];
    const float* weight = (const float*)d_in[1];
    const float* bias   = (const float*)d_in[2];
    const float* shifts = (const float*)d_in[3];
    float* out = (float*)d_out;

    const size_t xsp_elems = (size_t)6 * NB * HH * WW * 32;   // u16, 100.7 MB
    const size_t need2 = xsp_elems * 2 + 110592 * 2;

    if (ws_size >= need2) {
        unsigned short* xsp  = (unsigned short*)d_ws;
        unsigned short* wbuf = xsp + xsp_elems;
        prep_w2<<<432, 256, 0, stream>>>(weight, wbuf);
        shift_pow3<<<2 * NB * HH, 256, 0, stream>>>(x, shifts, xsp);
        conv2h<<<1024, 256, 0, stream>>>(xsp, wbuf, bias, out);
    } else {
        unsigned short* wbuf = (unsigned short*)d_ws;
        prep_w3<<<432, 256, 0, stream>>>(weight, wbuf);
        conv_f<<<1024, 256, 0, stream>>>(x, shifts, wbuf, bias, out);
    }
}

// Round 19
// 93.063 us; speedup vs baseline: 1.7703x; 1.7703x over previous
//
#include <hip/hip_runtime.h>
#include <hip/hip_bf16.h>
#include <math.h>

#define NB 16
#define C_IN 64
#define C_OUT 64
#define HH 128
#define WW 128
#define MAX_SHIFT 4.0f

typedef __attribute__((ext_vector_type(8))) short bf16x8;
typedef __attribute__((ext_vector_type(4))) float f32x4;
typedef __attribute__((ext_vector_type(4))) unsigned int u32x4;

__device__ inline unsigned short bf16_rne(float f) {
    unsigned u = __builtin_bit_cast(unsigned, f);
    u += 0x7fffu + ((u >> 16) & 1u);
    return (unsigned short)(u >> 16);
}
__device__ inline unsigned pack_bf16x2(float lo, float hi) {
    unsigned ul = __builtin_bit_cast(unsigned, lo);
    unsigned uh = __builtin_bit_cast(unsigned, hi);
    ul += 0x7fffu + ((ul >> 16) & 1u);
    uh += 0x7fffu + ((uh >> 16) & 1u);
    return (ul >> 16) | (uh & 0xffff0000u);
}

// =====================================================================
// PASS 1: bilinear + powers -> xsp[kb6][n][h][w][32] bf16 (kb-major, 100.7MB)
//   k = p*64 + c  =>  kb = 2p + cg,  slot = c%32
//   block = (cg, n, h); XCD-chunk-swizzled so neighbor-h share an L2
// =====================================================================
#define VSTR 34   // u16 stride per w (17 u32, odd -> conflict-free)

__global__ __launch_bounds__(256)
void shift_pow3(const float* __restrict__ x, const float* __restrict__ shifts,
                unsigned short* __restrict__ xsp) {
    __shared__ unsigned short row[128 * VSTR];   // 8,704 B
    __shared__ float s_fx[C_IN], s_fy[C_IN];
    __shared__ int s_dx[C_IN], s_dy[C_IN];

    // chunked bijective XCD swizzle: 4096 = 8 * 512
    int bid0 = blockIdx.x;
    int bid = (bid0 & 7) * 512 + (bid0 >> 3);
    int h  = bid & 127;
    int n  = (bid >> 7) & 15;
    int cg = bid >> 11;
    int tid = threadIdx.x;
    int wv = tid >> 6;
    int l  = tid & 63;

    if (tid < C_IN) {
        float sx = shifts[2 * tid] * MAX_SHIFT;
        float sy = shifts[2 * tid + 1] * MAX_SHIFT;
        float fx0 = floorf(sx), fy0 = floorf(sy);
        s_dx[tid] = (int)fx0; s_dy[tid] = (int)fy0;
        s_fx[tid] = sx - fx0;  s_fy[tid] = sy - fy0;
    }
    __syncthreads();

    const float* xn = x + (size_t)n * (C_IN * HH * WW);

    #pragma unroll 4
    for (int it = 0; it < 8; ++it) {
        int c32 = it * 4 + wv;                 // 0..31, wave-uniform
        int c   = cg * 32 + c32;
        int dx = s_dx[c], dy = s_dy[c];
        float fx = s_fx[c], fy = s_fy[c];
        const float* xp = xn + (size_t)c * (HH * WW);
        int y0 = h + dy, y1 = y0 + 1;
        bool vy0 = ((unsigned)y0 < (unsigned)HH);
        bool vy1 = ((unsigned)y1 < (unsigned)HH);
        const float* r0 = xp + y0 * WW;
        const float* r1 = xp + y1 * WW;

        #pragma unroll
        for (int hf = 0; hf < 2; ++hf) {
            int w = hf * 64 + l;
            int x0 = w + dx, x1 = x0 + 1;
            bool vx0 = ((unsigned)x0 < (unsigned)WW);
            bool vx1 = ((unsigned)x1 < (unsigned)WW);
            float v00 = (vy0 && vx0) ? r0[x0] : 0.f;
            float v01 = (vy0 && vx1) ? r0[x1] : 0.f;
            float v10 = (vy1 && vx0) ? r1[x0] : 0.f;
            float v11 = (vy1 && vx1) ? r1[x1] : 0.f;
            float v = (1.f - fy) * ((1.f - fx) * v00 + fx * v01)
                    + fy * ((1.f - fx) * v10 + fx * v11);
            row[w * VSTR + c32] = bf16_rne(v);
        }
    }
    __syncthreads();

    // writeout: 3 kb-slabs; each 2048 u32 = 8KB contiguous; powers on the fly
    const unsigned* rp = (const unsigned*)row;     // stride 17 u32 per w
    unsigned* xsp32 = (unsigned*)xsp;
    #pragma unroll 1
    for (int p = 0; p < 3; ++p) {
        int kb = p * 2 + cg;
        unsigned* dst = xsp32 + (size_t)(kb * (NB * HH) + n * HH + h) * 2048;
        #pragma unroll
        for (int itw = 0; itw < 8; ++itw) {
            int o32 = itw * 256 + tid;        // 0..2047
            int wl = o32 >> 4;
            int c4 = o32 & 15;
            unsigned u = rp[wl * 17 + c4];
            if (p != 0) {
                float f0 = __builtin_bit_cast(float, u << 16);
                float f1 = __builtin_bit_cast(float, u & 0xffff0000u);
                float r0 = f0 * f0, r1 = f1 * f1;
                if (p == 2) { r0 *= f0; r1 *= f1; }
                u = pack_bf16x2(r0, r1);
            }
            dst[o32] = u;
        }
    }
}

// =====================================================================
// weight prep: [t9][kb6][mf4][lane64][e8] bf16 ; k = kb*32 + slot
// =====================================================================
__global__ void prep_w2(const float* __restrict__ w, unsigned short* __restrict__ wbuf) {
    int id = blockIdx.x * 256 + threadIdx.x;   // < 110592
    int e = id & 7;
    int l = (id >> 3) & 63;
    int f = id >> 9;          // 0..215
    int mf = f & 3;
    int f2 = f >> 2;          // 0..53
    int kb = f2 % 6;
    int t  = f2 / 6;
    int k  = kb * 32 + (l >> 4) * 8 + e;   // 0..191
    int p  = k >> 6;
    int c  = k & 63;
    int co = mf * 16 + (l & 15);
    wbuf[id] = bf16_rne(w[(co * 192 + p * 64 + c) * 9 + t]);
}

// =====================================================================
// PASS 2: conv2i — 128-thread blocks (2 waves), 8x16 tile, grid 2048.
//   8 independent barrier domains per CU at the same 16 waves/CU.
//   LDS [10*18 px][44 u16] = 15,840 B.
// =====================================================================
__global__ __launch_bounds__(128, 4)
void conv2i(const unsigned short* __restrict__ xsp,
            const unsigned short* __restrict__ wbuf,
            const float* __restrict__ bias,
            float* __restrict__ out) {
    __shared__ unsigned short tile[180 * 44];   // 15,840 B

    int bid = blockIdx.x;
    int wg = (bid & 7) * 256 + (bid >> 3);   // bijective XCD swizzle (2048 = 8*256)
    int n  = wg >> 7;
    int t7 = wg & 127;
    int i0 = (t7 >> 3) * 8;        // 16 row-tiles of 8
    int j0 = (t7 & 7) * 16;        // 8 col-tiles of 16

    int tid = threadIdx.x;
    int l  = tid & 63;
    int wv = tid >> 6;             // 0..1
    int lm = l & 15;
    int lg = l >> 4;

    f32x4 acc[4][4];      // [mf][nf=row]
    #pragma unroll
    for (int mf = 0; mf < 4; ++mf) {
        #pragma unroll
        for (int r = 0; r < 4; ++r) {
            float bv = bias[mf * 16 + lg * 4 + r];
            #pragma unroll
            for (int nf = 0; nf < 4; ++nf) acc[mf][nf][r] = bv;
        }
    }

    int lds_base = (wv * 4 * 18 + lm) * 88 + lg * 16;   // bytes

    #pragma unroll 1
    for (int kb = 0; kb < 6; ++kb) {
        const unsigned short* xr = xsp + (size_t)(kb * NB + n) * (HH * WW * 32);
        __syncthreads();
        // ---- stage: 10 rows x 18 px x 64 B = 720 items of 16 B ----
        #pragma unroll
        for (int it = 0; it < 6; ++it) {
            int ch = it * 128 + tid;          // 0..767, need 720
            if (ch < 720) {
                int rr  = ch / 72;
                int rem = ch - rr * 72;
                int pxr = rem >> 2, sub = rem & 3;
                int gi = i0 - 1 + rr, gj = j0 - 1 + pxr;
                u32x4 d = {0, 0, 0, 0};
                if ((unsigned)gi < (unsigned)HH && (unsigned)gj < (unsigned)WW)
                    d = *(const u32x4*)(xr + ((size_t)gi * WW + gj) * 32 + sub * 8);
                *(u32x4*)((char*)tile + (rr * 18 + pxr) * 88 + sub * 16) = d;
            }
        }
        __syncthreads();

        // ---- compute: 9 taps x 4 nf x 4 mf MFMAs (prio-boosted) ----
        __builtin_amdgcn_s_setprio(1);
        bf16x8 Af[4];
        #pragma unroll
        for (int mf = 0; mf < 4; ++mf)
            Af[mf] = *(const bf16x8*)(wbuf + (size_t)((0 * 6 + kb) * 4 + mf) * 512 + l * 8);

        #pragma unroll 1
        for (int t = 0; t < 9; ++t) {
            bf16x8 Afn[4];
            int tn = (t < 8) ? t + 1 : t;
            #pragma unroll
            for (int mf = 0; mf < 4; ++mf)
                Afn[mf] = *(const bf16x8*)(wbuf + (size_t)((tn * 6 + kb) * 4 + mf) * 512 + l * 8);

            int ky = t / 3, kx = t - ky * 3;
            #pragma unroll
            for (int nf = 0; nf < 4; ++nf) {
                int off = lds_base + ((nf + ky) * 18 + kx) * 88;
                bf16x8 bfrag = *(const bf16x8*)((const char*)tile + off);
                #pragma unroll
                for (int mf = 0; mf < 4; ++mf)
                    acc[mf][nf] = __builtin_amdgcn_mfma_f32_16x16x32_bf16(Af[mf], bfrag, acc[mf][nf], 0, 0, 0);
            }
            #pragma unroll
            for (int mf = 0; mf < 4; ++mf) Af[mf] = Afn[mf];
        }
        __builtin_amdgcn_s_setprio(0);
    }

    // ---- epilogue ----
    #pragma unroll
    for (int mf = 0; mf < 4; ++mf) {
        #pragma unroll
        for (int nf = 0; nf < 4; ++nf) {
            int rowi = i0 + wv * 4 + nf;
            int col = j0 + lm;
            #pragma unroll
            for (int r = 0; r < 4; ++r) {
                int co = mf * 16 + lg * 4 + r;
                out[(((size_t)n * C_OUT + co) * HH + rowi) * WW + col] = acc[mf][nf][r];
            }
        }
    }
}

// =====================================================================
// Fallback: fused kernel (needs only 216 KB ws)
// =====================================================================
#define S_PX 100

__global__ void prep_w3(const float* __restrict__ w, unsigned short* __restrict__ wbuf) {
    int id = blockIdx.x * 256 + threadIdx.x;
    int e = id & 7;
    int l = (id >> 3) & 63;
    int f = id >> 9;
    int mf = f & 3;
    int f2 = f >> 2;
    int kb = f2 % 6;
    int t  = f2 / 6;
    int cg = kb / 3;
    int p  = kb - cg * 3;
    int cl = (l >> 4) * 8 + e;
    int co = mf * 16 + (l & 15);
    wbuf[id] = bf16_rne(w[(co * 192 + p * 64 + cg * 32 + cl) * 9 + t]);
}

__global__ __launch_bounds__(256, 2)
void conv_f(const float* __restrict__ x,
            const float* __restrict__ shifts,
            const unsigned short* __restrict__ wbuf,
            const float* __restrict__ bias,
            float* __restrict__ out) {
    __shared__ unsigned short tile[324 * S_PX];
    __shared__ float s_fx[C_IN], s_fy[C_IN];
    __shared__ int s_dx[C_IN], s_dy[C_IN];

    int bid = blockIdx.x;
    int wg = (bid & 7) * 128 + (bid >> 3);
    int n  = wg >> 6;
    int t6 = wg & 63;
    int i0 = (t6 >> 3) * 16;
    int j0 = (t6 & 7) * 16;

    int tid = threadIdx.x;
    int l  = tid & 63;
    int wv = tid >> 6;
    int lm = l & 15;
    int lg = l >> 4;

    if (tid < C_IN) {
        float sx = shifts[2 * tid] * MAX_SHIFT;
        float sy = shifts[2 * tid + 1] * MAX_SHIFT;
        float fx0 = floorf(sx), fy0 = floorf(sy);
        s_dx[tid] = (int)fx0; s_dy[tid] = (int)fy0;
        s_fx[tid] = sx - fx0;  s_fy[tid] = sy - fy0;
    }

    f32x4 acc[4][4];
    #pragma unroll
    for (int mf = 0; mf < 4; ++mf) {
        #pragma unroll
        for (int r = 0; r < 4; ++r) {
            float bv = bias[mf * 16 + lg * 4 + r];
            #pragma unroll
            for (int nf = 0; nf < 4; ++nf) acc[mf][nf][r] = bv;
        }
    }

    const float* xn = x + (size_t)n * (C_IN * HH * WW);

    #pragma unroll 1
    for (int cg = 0; cg < 2; ++cg) {
        __syncthreads();
        #pragma unroll 2
        for (int it = 0; it < 21; ++it) {
            int item = it * 256 + tid;
            if (item < 5184) {
                int cl  = item / 162;
                int rem = item - cl * 162;
                int rp  = rem / 18;
                int cc  = rem - rp * 18;
                int c   = cg * 32 + cl;
                int dx = s_dx[c], dy = s_dy[c];
                float fx = s_fx[c], fy = s_fy[c];
                const float* xp = xn + (size_t)c * (HH * WW);

                int gj  = j0 - 1 + cc;
                int xx0 = gj + dx, xx1 = xx0 + 1;
                bool vx0 = ((unsigned)xx0 < (unsigned)WW);
                bool vx1 = ((unsigned)xx1 < (unsigned)WW);
                int gi0 = i0 - 1 + rp * 2;
                int y0  = gi0 + dy;
                bool vyA = ((unsigned)y0 < (unsigned)HH);
                bool vyB = ((unsigned)(y0 + 1) < (unsigned)HH);
                bool vyC = ((unsigned)(y0 + 2) < (unsigned)HH);
                const float* rA = xp + y0 * WW;
                const float* rB = rA + WW;
                const float* rC = rB + WW;
                float m0 = (vyA && vx0) ? rA[xx0] : 0.f;
                float m1 = (vyA && vx1) ? rA[xx1] : 0.f;
                float m2 = (vyB && vx0) ? rB[xx0] : 0.f;
                float m3 = (vyB && vx1) ? rB[xx1] : 0.f;
                float m4 = (vyC && vx0) ? rC[xx0] : 0.f;
                float m5 = (vyC && vx1) ? rC[xx1] : 0.f;
                float hA = (1.f - fx) * m0 + fx * m1;
                float hB = (1.f - fx) * m2 + fx * m3;
                float hC = (1.f - fx) * m4 + fx * m5;
                float vT = (1.f - fy) * hA + fy * hB;
                float vU = (1.f - fy) * hB + fy * hC;
                if (!((unsigned)gj < (unsigned)WW))        { vT = 0.f; vU = 0.f; }
                if (!((unsigned)gi0 < (unsigned)HH))       vT = 0.f;
                if (!((unsigned)(gi0 + 1) < (unsigned)HH)) vU = 0.f;

                float t2 = vT * vT, t3 = t2 * vT;
                float u2 = vU * vU, u3 = u2 * vU;
                unsigned short* recT = tile + (rp * 2 * 18 + cc) * S_PX;
                unsigned short* recU = recT + 18 * S_PX;
                recT[cl]      = bf16_rne(vT);
                recT[32 + cl] = bf16_rne(t2);
                recT[64 + cl] = bf16_rne(t3);
                recU[cl]      = bf16_rne(vU);
                recU[32 + cl] = bf16_rne(u2);
                recU[64 + cl] = bf16_rne(u3);
            }
        }
        __syncthreads();

        #pragma unroll 1
        for (int p = 0; p < 3; ++p) {
            int kb = cg * 3 + p;
            #pragma unroll 1
            for (int t = 0; t < 9; ++t) {
                bf16x8 Af[4];
                #pragma unroll
                for (int mf = 0; mf < 4; ++mf)
                    Af[mf] = *(const bf16x8*)(wbuf + (size_t)((t * 6 + kb) * 4 + mf) * 512 + l * 8);

                int ky = t / 3, kx = t - ky * 3;
                #pragma unroll
                for (int nf = 0; nf < 4; ++nf) {
                    int off = ((wv * 4 + nf + ky) * 18 + (lm + kx)) * 200 + p * 64 + lg * 16;
                    bf16x8 bfrag = *(const bf16x8*)((const char*)tile + off);
                    #pragma unroll
                    for (int mf = 0; mf < 4; ++mf)
                        acc[mf][nf] = __builtin_amdgcn_mfma_f32_16x16x32_bf16(Af[mf], bfrag, acc[mf][nf], 0, 0, 0);
                }
            }
        }
    }

    #pragma unroll
    for (int mf = 0; mf < 4; ++mf) {
        #pragma unroll
        for (int nf = 0; nf < 4; ++nf) {
            int rowi = i0 + wv * 4 + nf;
            int col = j0 + lm;
            #pragma unroll
            for (int r = 0; r < 4; ++r) {
                int co = mf * 16 + lg * 4 + r;
                out[(((size_t)n * C_OUT + co) * HH + rowi) * WW + col] = acc[mf][nf][r];
            }
        }
    }
}

extern "C" void kernel_launch(void* const* d_in, const int* in_sizes, int n_in,
                              void* d_out, int out_size, void* d_ws, size_t ws_size,
                              hipStream_t stream) {
    (void)in_sizes; (void)n_in; (void)out_size;
    const float* x      = (const float*)d_in[0];
    const float* weight = (const float*)d_in[1];
    const float* bias   = (const float*)d_in[2];
    const float* shifts = (const float*)d_in[3];
    float* out = (float*)d_out;

    const size_t xsp_elems = (size_t)6 * NB * HH * WW * 32;   // u16, 100.7 MB
    const size_t need2 = xsp_elems * 2 + 110592 * 2;

    if (ws_size >= need2) {
        unsigned short* xsp  = (unsigned short*)d_ws;
        unsigned short* wbuf = xsp + xsp_elems;
        prep_w2<<<432, 256, 0, stream>>>(weight, wbuf);
        shift_pow3<<<2 * NB * HH, 256, 0, stream>>>(x, shifts, xsp);
        conv2i<<<2048, 128, 0, stream>>>(xsp, wbuf, bias, out);
    } else {
        unsigned short* wbuf = (unsigned short*)d_ws;
        prep_w3<<<432, 256, 0, stream>>>(weight, wbuf);
        conv_f<<<1024, 256, 0, stream>>>(x, shifts, wbuf, bias, out);
    }
}